// Round 7
// baseline (335.194 us; speedup 1.0000x reference)
//
#include <hip/hip_runtime.h>
#include <hip/hip_bf16.h>

#define NN 50000
#define CH 256            // output channels of both layers
#define SLOTS 64          // ELL row capacity (max in-degree ~35 for E=8n random)

typedef unsigned short u16;
typedef unsigned int   u32;

using short8 = __attribute__((ext_vector_type(8))) short;
using u16x8  = __attribute__((ext_vector_type(8))) unsigned short;
using f32x4  = __attribute__((ext_vector_type(4))) float;

static __device__ __forceinline__ float4 ld4(const float* p){ return *(const float4*)p; }

// fp32 -> bf16 round-to-nearest-even (scalar)
static __device__ __forceinline__ u16 f2b(float f){
  u32 u = __float_as_uint(f);
  u = (u + 0x7fffu + ((u >> 16) & 1u)) >> 16;
  return (u16)u;
}
static __device__ __forceinline__ float b2f(u16 b){
  return __uint_as_float(((u32)b) << 16);
}
// packed RNE cvt: 2 floats -> 1 dword of bf16 (v_cvt_pk_bf16_f32)
static __device__ __forceinline__ int pkbf(float lo, float hi){
  __hip_bfloat162 h = __float22bfloat162_rn(make_float2(lo, hi));
  int r; __builtin_memcpy(&r, &h, 4); return r;
}

// ---------------- ELL build (+ piggybacked W2 fp32->bf16 cvt) ----------------

__global__ void ell_build_kernel(const int* __restrict__ src, const int* __restrict__ dst,
                                 int* __restrict__ deg, int* __restrict__ ell, int E,
                                 const float* __restrict__ W2, u16* __restrict__ W2bf, int w2n4){
  int T = gridDim.x * 256;
  int g = blockIdx.x*256 + threadIdx.x;
  if (g < E){
    int d = dst[g];
    int pos = atomicAdd(&deg[d], 1);
    if (pos < SLOTS) ell[(size_t)d*SLOTS + pos] = src[g];
  }
  for (int i = g; i < w2n4; i += T){
    float4 v = ld4(W2 + (size_t)i*4);
    ushort4 o; o.x=f2b(v.x); o.y=f2b(v.y); o.z=f2b(v.z); o.w=f2b(v.w);
    *(ushort4*)(W2bf + (size_t)i*4) = o;
  }
}

// ---------------- gemm1: fp32 inputs, 64x64x32 tile, reg-staged packed cvt ----------------
// C[m][n] = sum_k A[m*K+k]*B[n*K+k], bf16 out. 256 thr = 4 waves, wave does 32x32.
// blockIdx.x = bn (4), blockIdx.y = bm (782) -> blocks sharing an A-tile co-scheduled.
// LDS row stride 40 elems (80 B) -> ds_read conflicts 8-way -> 2-way (free).

#define LSTR 40

__global__ __launch_bounds__(256) void gemm1_kernel(const float* __restrict__ A,
                                                    const float* __restrict__ B,
                                                    u16* __restrict__ C,
                                                    int M, int K){
  __shared__ u16 As[64*LSTR];
  __shared__ u16 Bs[64*LSTR];
  int tid = threadIdx.x;
  int wave = tid >> 6, lane = tid & 63;
  int bn = blockIdx.x, bm = blockIdx.y;

  int sr = tid >> 2;          // 0..63 staging row
  int sc = (tid & 3) * 8;     // 0,8,16,24 k-offset (8 floats)
  int rA = bm*64 + sr;  if (rA > M-1) rA = M-1;
  const float* ga = A + (size_t)rA*K + sc;
  const float* gb = B + (size_t)(bn*64 + sr)*K + sc;

  int wm = wave & 1, wn = wave >> 1;
  int lm = lane & 15;
  int lk = (lane >> 4) * 8;

  f32x4 acc[2][2] = {};

  for (int k0 = 0; k0 < K; k0 += 32){
    float4 a0 = ld4(ga + k0), a1 = ld4(ga + k0 + 4);
    float4 b0 = ld4(gb + k0), b1 = ld4(gb + k0 + 4);
    int4 wa = { pkbf(a0.x,a0.y), pkbf(a0.z,a0.w), pkbf(a1.x,a1.y), pkbf(a1.z,a1.w) };
    int4 wb = { pkbf(b0.x,b0.y), pkbf(b0.z,b0.w), pkbf(b1.x,b1.y), pkbf(b1.z,b1.w) };
    *(int4*)&As[(size_t)sr*LSTR + sc] = wa;
    *(int4*)&Bs[(size_t)sr*LSTR + sc] = wb;
    __syncthreads();
    short8 af[2], bfr[2];
    #pragma unroll
    for (int i=0;i<2;i++)
      af[i] = *(const short8*)&As[(size_t)(wm*32 + i*16 + lm)*LSTR + lk];
    #pragma unroll
    for (int j=0;j<2;j++)
      bfr[j] = *(const short8*)&Bs[(size_t)(wn*32 + j*16 + lm)*LSTR + lk];
    #pragma unroll
    for (int i=0;i<2;i++)
      #pragma unroll
      for (int j=0;j<2;j++)
        acc[i][j] = __builtin_amdgcn_mfma_f32_16x16x32_bf16(af[i], bfr[j], acc[i][j], 0, 0, 0);
    __syncthreads();
  }

  // C/D layout: row=(lane>>4)*4+reg, col=lane&15 (m89-verified)
  int rb = (lane >> 4) * 4;
  #pragma unroll
  for (int i=0;i<2;i++){
    #pragma unroll
    for (int r=0;r<4;r++){
      int row = bm*64 + wm*32 + i*16 + rb + r;
      if (row < M){
        #pragma unroll
        for (int j=0;j<2;j++){
          int col = bn*64 + wn*32 + j*16 + lm;
          C[(size_t)row*CH + col] = f2b(acc[i][j][r]);
        }
      }
    }
  }
}

// ---------------- gemm2: bf16 inputs, 64x64x32 tile, global_load_lds staging ----------------

static __device__ __forceinline__ void gload_lds16(const u16* g, u16* l){
  __builtin_amdgcn_global_load_lds((const __attribute__((address_space(1))) void*)g,
                                   (__attribute__((address_space(3))) void*)l, 16, 0, 0);
}

__global__ __launch_bounds__(256) void gemm2_kernel(const u16* __restrict__ A,
                                                    const u16* __restrict__ B,
                                                    u16* __restrict__ C,
                                                    int M, int K){
  __shared__ u16 As[64*32];
  __shared__ u16 Bs[64*32];
  int tid = threadIdx.x;
  int wave = tid >> 6, lane = tid & 63;
  int bn = blockIdx.x, bm = blockIdx.y;

  int sr = tid >> 2;          // 0..63
  int sc = (tid & 3) * 8;
  int rA = bm*64 + sr;  if (rA > M-1) rA = M-1;
  const u16* ga = A + (size_t)rA*K + sc;
  const u16* gb = B + (size_t)(bn*64 + sr)*K + sc;
  // wave-uniform LDS dest: lane*16B covers exactly this wave's 16 rows
  u16* la = As + (size_t)wave*512;   // 64 lanes * 8 elems
  u16* lb = Bs + (size_t)wave*512;

  int wm = wave & 1, wn = wave >> 1;
  int lm = lane & 15;
  int lk = (lane >> 4) * 8;

  f32x4 acc[2][2] = {};

  for (int k0 = 0; k0 < K; k0 += 32){
    gload_lds16(ga + k0, la);
    gload_lds16(gb + k0, lb);
    __syncthreads();
    short8 af[2], bfr[2];
    #pragma unroll
    for (int i=0;i<2;i++)
      af[i] = *(const short8*)&As[(size_t)(wm*32 + i*16 + lm)*32 + lk];
    #pragma unroll
    for (int j=0;j<2;j++)
      bfr[j] = *(const short8*)&Bs[(size_t)(wn*32 + j*16 + lm)*32 + lk];
    #pragma unroll
    for (int i=0;i<2;i++)
      #pragma unroll
      for (int j=0;j<2;j++)
        acc[i][j] = __builtin_amdgcn_mfma_f32_16x16x32_bf16(af[i], bfr[j], acc[i][j], 0, 0, 0);
    __syncthreads();
  }

  int rb = (lane >> 4) * 4;
  #pragma unroll
  for (int i=0;i<2;i++){
    #pragma unroll
    for (int r=0;r<4;r++){
      int row = bm*64 + wm*32 + i*16 + rb + r;
      if (row < M){
        #pragma unroll
        for (int j=0;j<2;j++){
          int col = bn*64 + wn*32 + j*16 + lm;
          C[(size_t)row*CH + col] = f2b(acc[i][j][r]);
        }
      }
    }
  }
}

// ---------------- aggregation over ELL (bf16 in) ----------------
// out[i] = (relu?) sum_j h[ell[i][j]]*dinv[s]*dinv[i] + h[i]*dinv_i^2 + b
// one wave per node; half-wave (32 lanes x 16B) covers the 512B row.
// half h processes edge quads [8k+4h, 8k+4h+4) with one int4 index load.

template<bool RELU, bool OUTBF>
__global__ __launch_bounds__(256) void aggregate_kernel(const u16* __restrict__ h,
                                                        const float* __restrict__ bias,
                                                        const int* __restrict__ deg,
                                                        const int* __restrict__ ell,
                                                        void* __restrict__ outv, int n){
  int wave = threadIdx.x >> 6;
  int lane = threadIdx.x & 63;
  int i = blockIdx.x*4 + wave;
  if (i >= n) return;
  int half = lane >> 5;
  int c = (lane & 31) * 8;

  int degi = deg[i];
  float di = rsqrtf(1.0f + (float)degi);
  int m = degi < SLOTS ? degi : SLOTS;
  const int* row = ell + (size_t)i*SLOTS;

  float acc[8];
  #pragma unroll
  for (int k=0;k<8;k++) acc[k] = 0.f;

  int e = 0;
  for (; e + 7 < m; e += 8){
    int4 sv = *(const int4*)(row + e + half*4);   // 4 contiguous indices for this half
    float n0 = rsqrtf(1.0f + (float)deg[sv.x]) * di;
    float n1 = rsqrtf(1.0f + (float)deg[sv.y]) * di;
    float n2 = rsqrtf(1.0f + (float)deg[sv.z]) * di;
    float n3 = rsqrtf(1.0f + (float)deg[sv.w]) * di;
    u16x8 h0 = *(const u16x8*)(h + (size_t)sv.x*CH + c);
    u16x8 h1 = *(const u16x8*)(h + (size_t)sv.y*CH + c);
    u16x8 h2 = *(const u16x8*)(h + (size_t)sv.z*CH + c);
    u16x8 h3 = *(const u16x8*)(h + (size_t)sv.w*CH + c);
    #pragma unroll
    for (int k=0;k<8;k++) acc[k] += b2f(h0[k])*n0;
    #pragma unroll
    for (int k=0;k<8;k++) acc[k] += b2f(h1[k])*n1;
    #pragma unroll
    for (int k=0;k<8;k++) acc[k] += b2f(h2[k])*n2;
    #pragma unroll
    for (int k=0;k<8;k++) acc[k] += b2f(h3[k])*n3;
  }
  // remainder: stride-2 across halves
  for (int ee = e + half; ee < m; ee += 2){
    int s0 = row[ee];
    float n0 = rsqrtf(1.0f + (float)deg[s0]) * di;
    u16x8 h0 = *(const u16x8*)(h + (size_t)s0*CH + c);
    #pragma unroll
    for (int k=0;k<8;k++) acc[k] += b2f(h0[k])*n0;
  }

  if (half == 0){
    float w = di*di;
    float4 b0 = ld4(bias + c), b1 = ld4(bias + c + 4);
    u16x8 hv = *(const u16x8*)(h + (size_t)i*CH + c);
    acc[0] += b2f(hv[0])*w + b0.x; acc[1] += b2f(hv[1])*w + b0.y;
    acc[2] += b2f(hv[2])*w + b0.z; acc[3] += b2f(hv[3])*w + b0.w;
    acc[4] += b2f(hv[4])*w + b1.x; acc[5] += b2f(hv[5])*w + b1.y;
    acc[6] += b2f(hv[6])*w + b1.z; acc[7] += b2f(hv[7])*w + b1.w;
  }

  #pragma unroll
  for (int k=0;k<8;k++) acc[k] += __shfl_xor(acc[k], 32, 64);

  if (half == 0){
    if (RELU){
      #pragma unroll
      for (int k=0;k<8;k++) acc[k] = fmaxf(acc[k], 0.f);
    }
    if (OUTBF){
      u16x8 o;
      #pragma unroll
      for (int k=0;k<8;k++) o[k] = f2b(acc[k]);
      *(u16x8*)((u16*)outv + (size_t)i*CH + c) = o;
    } else {
      float* op = (float*)outv + (size_t)i*CH + c;
      *(float4*)op       = make_float4(acc[0],acc[1],acc[2],acc[3]);
      *(float4*)(op + 4) = make_float4(acc[4],acc[5],acc[6],acc[7]);
    }
  }
}

// ---------------- launch ----------------

extern "C" void kernel_launch(void* const* d_in, const int* in_sizes, int n_in,
                              void* d_out, int out_size, void* d_ws, size_t ws_size,
                              hipStream_t stream){
  const float* x  = (const float*)d_in[0];
  const int*   ei = (const int*)d_in[1];
  const float* W1 = (const float*)d_in[2];
  const float* b1 = (const float*)d_in[3];
  const float* W2 = (const float*)d_in[4];
  const float* b2 = (const float*)d_in[5];
  float* out = (float*)d_out;

  const int n = NN;
  const int E = in_sizes[1] / 2;
  const int* src = ei;
  const int* dst = ei + E;
  const int KIN = in_sizes[0] / n;   // 512

  char* ws = (char*)d_ws;
  size_t off = 0;
  auto alloc = [&](size_t bytes)->char* {
    char* p = ws + off;
    off += (bytes + 255) & ~(size_t)255;
    return p;
  };
  u16*   h1bf   = (u16*)  alloc((size_t)n*CH*sizeof(u16));       // 25.6 MB
  u16*   g2out  = (u16*)  alloc((size_t)n*CH*sizeof(u16));       // 25.6 MB
  u16*   W2bf   = (u16*)  alloc((size_t)CH*CH*sizeof(u16));
  int*   deg    = (int*)  alloc((size_t)n*sizeof(int));
  int*   ell    = (int*)  alloc((size_t)n*SLOTS*sizeof(int));    // 12.8 MB
  (void)ws_size;

  u16* g1out = (u16*)d_out;              // GEMM1 bf16 output parks in d_out

  // --- ELL adjacency ---
  hipMemsetAsync(deg, 0, (size_t)n*sizeof(int), stream);
  ell_build_kernel<<<(E+255)/256, 256, 0, stream>>>(src, dst, deg, ell, E, W2, W2bf, CH*CH/4);

  // --- layer 1: g1out = bf16(x) @ bf16(W1)^T ; h1bf = relu(agg(g1out)+b1) ---
  dim3 gg(CH/64, (n+63)/64);   // bn-major: A-tile sharers co-scheduled
  gemm1_kernel<<<gg, 256, 0, stream>>>(x, W1, g1out, n, KIN);
  aggregate_kernel<true, true><<<(n+3)/4, 256, 0, stream>>>(g1out, b1, deg, ell, h1bf, n);

  // --- layer 2: g2out = h1bf @ W2bf^T ; out = agg(g2out) + b2 ---
  gemm2_kernel<<<gg, 256, 0, stream>>>(h1bf, W2bf, g2out, n, CH);
  aggregate_kernel<false, false><<<(n+3)/4, 256, 0, stream>>>(g2out, b2, deg, ell, out, n);
}